// Round 1
// baseline (1280.290 us; speedup 1.0000x reference)
//
#include <hip/hip_runtime.h>
#include <hip/hip_bf16.h>
#include <math.h>

#define N_NODES 50000
#define E_EDGES 800000
#define D_DIM   128
#define H_HEADS 8

static __device__ __forceinline__ float4 ldg4(const float* p) {
    return *reinterpret_cast<const float4*>(p);
}

// ---------------- histogram of dst ----------------
__global__ void hist_kernel(const int* __restrict__ dst, int* __restrict__ hist) {
    int i = blockIdx.x * blockDim.x + threadIdx.x;
    if (i < E_EDGES) atomicAdd(&hist[dst[i]], 1);
}

// ---------------- exclusive scan over N_NODES (single block) ----------------
__global__ __launch_bounds__(1024) void scan_kernel(const int* __restrict__ cnt,
                                                    int* __restrict__ start,
                                                    int* __restrict__ cursor) {
    __shared__ int sh[1024];
    const int t = threadIdx.x;
    const int CPT = (N_NODES + 1023) / 1024;
    int lo = t * CPT;
    int hi = lo + CPT; if (hi > N_NODES) hi = N_NODES; if (lo > N_NODES) lo = N_NODES;
    int s = 0;
    for (int i = lo; i < hi; i++) s += cnt[i];
    sh[t] = s;
    __syncthreads();
    for (int off = 1; off < 1024; off <<= 1) {
        int v = (t >= off) ? sh[t - off] : 0;
        __syncthreads();
        sh[t] += v;
        __syncthreads();
    }
    int excl = sh[t] - s;
    int run = excl;
    for (int i = lo; i < hi; i++) {
        start[i]  = run;
        cursor[i] = run;
        run += cnt[i];
    }
    if (t == 1023) start[N_NODES] = sh[1023];
}

// ---------------- scatter edge ids into dst-sorted order ----------------
__global__ void scatter_kernel(const int* __restrict__ dst, int* __restrict__ cursor,
                               int* __restrict__ eids) {
    int i = blockIdx.x * blockDim.x + threadIdx.x;
    if (i < E_EDGES) {
        int p = atomicAdd(&cursor[dst[i]], 1);
        eids[p] = i;
    }
}

// ---------------- generic f32 GEMM: C[M x colsTotal] = A[M x K] @ W[K x colsTotal] ----------------
// optional bias[colsTotal], relu, residual[M x colsTotal]
__global__ __launch_bounds__(256) void gemm_f32(const float* __restrict__ A,
                                                const float* __restrict__ W,
                                                const float* __restrict__ bias,
                                                const float* __restrict__ resid,
                                                float* __restrict__ C,
                                                int M, int K, int colsTotal, int doRelu) {
    __shared__ float As[32][128];   // k-major transposed A chunk
    __shared__ float Ws[32][128];
    const int tid  = threadIdx.x;
    const int row0 = blockIdx.x * 128;
    const int c0   = blockIdx.y * 128;
    const int tx = tid & 15;        // col group
    const int ty = tid >> 4;        // row group
    float acc[8][8];
#pragma unroll
    for (int i = 0; i < 8; i++)
#pragma unroll
        for (int j = 0; j < 8; j++) acc[i][j] = 0.f;

    for (int k0 = 0; k0 < K; k0 += 32) {
        __syncthreads();
#pragma unroll
        for (int m = 0; m < 4; m++) {
            int i = tid + 256 * m;
            {   // A chunk: 128 rows x 32 k  (1024 float4)
                int r  = i >> 3;
                int k4 = (i & 7) * 4;
                float4 v = make_float4(0.f, 0.f, 0.f, 0.f);
                if (row0 + r < M) v = ldg4(&A[(size_t)(row0 + r) * K + k0 + k4]);
                As[k4 + 0][r] = v.x; As[k4 + 1][r] = v.y;
                As[k4 + 2][r] = v.z; As[k4 + 3][r] = v.w;
            }
            {   // W chunk: 32 rows x 128 cols (1024 float4)
                int r  = i >> 5;
                int c4 = (i & 31) * 4;
                float4 v = ldg4(&W[(size_t)(k0 + r) * colsTotal + c0 + c4]);
                *reinterpret_cast<float4*>(&Ws[r][c4]) = v;
            }
        }
        __syncthreads();
#pragma unroll
        for (int kk = 0; kk < 32; kk++) {
            float a[8], b[8];
#pragma unroll
            for (int i = 0; i < 4; i++) {
                float2 t2 = *reinterpret_cast<const float2*>(&As[kk][ty * 8 + 2 * i]);
                a[2 * i] = t2.x; a[2 * i + 1] = t2.y;
            }
#pragma unroll
            for (int j = 0; j < 4; j++) {
                float2 t2 = *reinterpret_cast<const float2*>(&Ws[kk][tx * 2 + 32 * j]);
                b[2 * j] = t2.x; b[2 * j + 1] = t2.y;
            }
#pragma unroll
            for (int i = 0; i < 8; i++)
#pragma unroll
                for (int j = 0; j < 8; j++)
                    acc[i][j] = fmaf(a[i], b[j], acc[i][j]);
        }
    }
    // epilogue: col(jj) = c0 + tx*2 + 32*(jj>>1) + (jj&1)
#pragma unroll
    for (int i = 0; i < 8; i++) {
        int r = row0 + ty * 8 + i;
        if (r < M) {
#pragma unroll
            for (int jj = 0; jj < 8; jj += 2) {
                int c = c0 + tx * 2 + 32 * (jj >> 1);
                float2 v;
                v.x = acc[i][jj];
                v.y = acc[i][jj + 1];
                if (bias) { v.x += bias[c]; v.y += bias[c + 1]; }
                if (doRelu) { v.x = fmaxf(v.x, 0.f); v.y = fmaxf(v.y, 0.f); }
                if (resid) {
                    float2 rv = *reinterpret_cast<const float2*>(&resid[(size_t)r * colsTotal + c]);
                    v.x += rv.x; v.y += rv.y;
                }
                *reinterpret_cast<float2*>(&C[(size_t)r * colsTotal + c]) = v;
            }
        }
    }
}

// ---------------- edge kernel: fused ef = e@We and score -> s = exp(clamp(...)) ----------------
// block: 64 edges, 8 waves (one head per wave). S layout: [H][E]
__global__ __launch_bounds__(512) void edge_kernel(const float* __restrict__ e,
                                                   const int* __restrict__ src,
                                                   const int* __restrict__ dst,
                                                   const float* __restrict__ Q,
                                                   const float* __restrict__ Km,
                                                   const float* __restrict__ We,
                                                   float* __restrict__ S) {
    __shared__ float es[64][129];
    const int lx = threadIdx.x;   // edge in tile
    const int w  = threadIdx.y;   // head
    const int e0 = blockIdx.x * 64;
    {   // stage e tile: 64 x 128 floats
        int t = w * 64 + lx;
#pragma unroll
        for (int m = 0; m < 4; m++) {
            int i  = t + 512 * m;
            int r  = i >> 5;
            int c4 = (i & 31) * 4;
            float4 v = ldg4(&e[(size_t)(e0 + r) * 128 + c4]);
            es[r][c4 + 0] = v.x; es[r][c4 + 1] = v.y;
            es[r][c4 + 2] = v.z; es[r][c4 + 3] = v.w;
        }
    }
    __syncthreads();
    const int edge = e0 + lx;
    const int si = src[edge];
    const int di = dst[edge];
    const int h16 = w * 16;
    float kq[16];
    {
        const float* kp = &Km[(size_t)si * 128 + h16];
        const float* qp = &Q[(size_t)di * 128 + h16];
#pragma unroll
        for (int m = 0; m < 4; m++) {
            float4 kv = ldg4(kp + 4 * m);
            float4 qv = ldg4(qp + 4 * m);
            kq[4 * m + 0] = kv.x * qv.x * 0.25f;
            kq[4 * m + 1] = kv.y * qv.y * 0.25f;
            kq[4 * m + 2] = kv.z * qv.z * 0.25f;
            kq[4 * m + 3] = kv.w * qv.w * 0.25f;
        }
    }
    // wave-uniform We row base -> scalar loads
    const int hh16 = __builtin_amdgcn_readfirstlane(w) * 16;
    float acc = 0.f;
    for (int c = 0; c < 128; c++) {
        const float* wr = &We[(size_t)c * 128 + hh16];
        float4 w0 = ldg4(wr + 0), w1 = ldg4(wr + 4), w2 = ldg4(wr + 8), w3 = ldg4(wr + 12);
        float t;
        t  = w0.x * kq[0];  t = fmaf(w0.y, kq[1], t);  t = fmaf(w0.z, kq[2], t);  t = fmaf(w0.w, kq[3], t);
        t  = fmaf(w1.x, kq[4], t);  t = fmaf(w1.y, kq[5], t);  t = fmaf(w1.z, kq[6], t);  t = fmaf(w1.w, kq[7], t);
        t  = fmaf(w2.x, kq[8], t);  t = fmaf(w2.y, kq[9], t);  t = fmaf(w2.z, kq[10], t); t = fmaf(w2.w, kq[11], t);
        t  = fmaf(w3.x, kq[12], t); t = fmaf(w3.y, kq[13], t); t = fmaf(w3.z, kq[14], t); t = fmaf(w3.w, kq[15], t);
        acc = fmaf(es[lx][c], t, acc);
    }
    acc = fminf(fmaxf(acc, -5.f), 5.f);
    S[(size_t)w * E_EDGES + edge] = __expf(acc);
}

// ---------------- aggregation: per-dst-node sum over CSR edges ----------------
__global__ __launch_bounds__(128) void agg_kernel(const float* __restrict__ V,
                                                  const float* __restrict__ S,
                                                  const int* __restrict__ start,
                                                  const int* __restrict__ eids,
                                                  const int* __restrict__ src,
                                                  float* __restrict__ HA) {
    const int n = blockIdx.x;
    const int t = threadIdx.x;      // 0..127
    const int h = t >> 4;
    const int s0 = start[n];
    const int s1 = start[n + 1];
    float acc = 0.f, z = 0.f;
    for (int i = s0; i < s1; i++) {
        int eid = eids[i];
        float sv = S[(size_t)h * E_EDGES + eid];
        float vv = V[(size_t)src[eid] * 128 + t];
        acc = fmaf(sv, vv, acc);
        z += sv;
    }
    HA[(size_t)n * 128 + t] = acc / (z + 1e-6f);
}

// ---------------- batch norm ----------------
__global__ __launch_bounds__(256) void bn_stats(const float* __restrict__ X,
                                                float* __restrict__ sums) {
    __shared__ float s1[256], s2[256];
    const int tid = threadIdx.x;
    float a1 = 0.f, a2 = 0.f;
    const size_t total = (size_t)N_NODES * 128;
    for (size_t i = (size_t)blockIdx.x * 256 + tid; i < total; i += (size_t)gridDim.x * 256) {
        float v = X[i];
        a1 += v;
        a2 += v * v;
    }
    s1[tid] = a1; s2[tid] = a2;
    __syncthreads();
    if (tid < 128) {
        a1 = s1[tid] + s1[tid + 128];
        a2 = s2[tid] + s2[tid + 128];
        atomicAdd(&sums[tid], a1);
        atomicAdd(&sums[128 + tid], a2);
    }
}

__global__ void bn_finalize(const float* __restrict__ sums, float* __restrict__ mu_rstd) {
    int c = threadIdx.x;   // 128 threads
    float mu  = sums[c] * (1.f / (float)N_NODES);
    float var = sums[128 + c] * (1.f / (float)N_NODES) - mu * mu;
    mu_rstd[c]       = mu;
    mu_rstd[128 + c] = rsqrtf(var + 1e-5f);
}

__global__ __launch_bounds__(256) void bn_apply(const float* __restrict__ X,
                                                const float* __restrict__ mu_rstd,
                                                const float* __restrict__ gamma,
                                                const float* __restrict__ beta,
                                                float* __restrict__ Y) {
    const size_t total = (size_t)N_NODES * 128;
    const size_t step = (size_t)gridDim.x * blockDim.x * 4;
    for (size_t i = ((size_t)blockIdx.x * blockDim.x + threadIdx.x) * 4; i < total; i += step) {
        float4 x = ldg4(&X[i]);
        int c = (int)(i & 127);
        float4 y;
        y.x = (x.x - mu_rstd[c + 0]) * mu_rstd[128 + c + 0] * gamma[c + 0] + beta[c + 0];
        y.y = (x.y - mu_rstd[c + 1]) * mu_rstd[128 + c + 1] * gamma[c + 1] + beta[c + 1];
        y.z = (x.z - mu_rstd[c + 2]) * mu_rstd[128 + c + 2] * gamma[c + 2] + beta[c + 2];
        y.w = (x.w - mu_rstd[c + 3]) * mu_rstd[128 + c + 3] * gamma[c + 3] + beta[c + 3];
        *reinterpret_cast<float4*>(&Y[i]) = y;
    }
}

extern "C" void kernel_launch(void* const* d_in, const int* in_sizes, int n_in,
                              void* d_out, int out_size, void* d_ws, size_t ws_size,
                              hipStream_t stream) {
    (void)in_sizes; (void)n_in; (void)out_size; (void)ws_size;
    const int*   src   = (const int*)d_in[0];
    const int*   dst   = (const int*)d_in[1];
    const float* h     = (const float*)d_in[2];
    const float* e     = (const float*)d_in[3];
    const float* Wq    = (const float*)d_in[5];
    const float* Wk    = (const float*)d_in[6];
    const float* Wv    = (const float*)d_in[7];
    const float* We    = (const float*)d_in[8];
    const float* Wsdp  = (const float*)d_in[9];
    const float* bsdp  = (const float*)d_in[10];
    const float* Wh1   = (const float*)d_in[11];
    const float* bh1   = (const float*)d_in[12];
    const float* Wh2   = (const float*)d_in[13];
    const float* bh2   = (const float*)d_in[14];
    const float* gamma = (const float*)d_in[15];
    const float* beta  = (const float*)d_in[16];
    float* out = (float*)d_out;

    float* ws = (float*)d_ws;
    const size_t NM = (size_t)N_NODES * 128;   // 6.4M
    float* Qb    = ws;               // q; later h_attn
    float* Kb    = ws + NM;          // k; later bn1 input (pre-BN), later t2 (pre-BN2)
    float* Vb    = ws + 2 * NM;      // v; later bn1 output
    float* Sb    = ws + 3 * NM;      // edge scores [H][E]
    float* T1    = ws + 4 * NM;      // FFN hidden, N x 256 (2*NM)
    float* STATS = ws + 6 * NM;      // 1024 floats: sums1(256), mu_rstd1(256), sums2(256), mu_rstd2(256)
    int* hist   = (int*)(STATS + 1024);
    int* startp = hist + N_NODES;
    int* cursor = startp + N_NODES + 1;
    int* eids   = cursor + N_NODES;

    float* sums1 = STATS;
    float* mr1   = STATS + 256;
    float* sums2 = STATS + 512;
    float* mr2   = STATS + 768;

    // e pass-through output (independent)
    hipMemcpyAsync(out + NM, e, (size_t)E_EDGES * 128 * sizeof(float),
                   hipMemcpyDeviceToDevice, stream);

    // zero stats + histogram (contiguous region)
    hipMemsetAsync(STATS, 0, (1024 + N_NODES) * sizeof(float), stream);

    // CSR build
    hist_kernel<<<(E_EDGES + 255) / 256, 256, 0, stream>>>(dst, hist);
    scan_kernel<<<1, 1024, 0, stream>>>(hist, startp, cursor);
    scatter_kernel<<<(E_EDGES + 255) / 256, 256, 0, stream>>>(dst, cursor, eids);

    // projections q,k,v
    const int rowTiles = (N_NODES + 127) / 128;   // 391
    gemm_f32<<<dim3(rowTiles, 1), 256, 0, stream>>>(h, Wq, nullptr, nullptr, Qb, N_NODES, 128, 128, 0);
    gemm_f32<<<dim3(rowTiles, 1), 256, 0, stream>>>(h, Wk, nullptr, nullptr, Kb, N_NODES, 128, 128, 0);
    gemm_f32<<<dim3(rowTiles, 1), 256, 0, stream>>>(h, Wv, nullptr, nullptr, Vb, N_NODES, 128, 128, 0);

    // edge scores (fused ef = e @ We)
    edge_kernel<<<E_EDGES / 64, dim3(64, 8), 0, stream>>>(e, src, dst, Qb, Kb, We, Sb);

    // aggregation -> h_attn (into Qb)
    agg_kernel<<<N_NODES, 128, 0, stream>>>(Vb, Sb, startp, eids, src, Qb);

    // sdp projection + residual h -> Kb (pre-BN1)
    gemm_f32<<<dim3(rowTiles, 1), 256, 0, stream>>>(Qb, Wsdp, bsdp, h, Kb, N_NODES, 128, 128, 0);

    // BN1 -> Vb
    bn_stats<<<512, 256, 0, stream>>>(Kb, sums1);
    bn_finalize<<<1, 128, 0, stream>>>(sums1, mr1);
    bn_apply<<<2048, 256, 0, stream>>>(Kb, mr1, gamma, beta, Vb);

    // FFN: T1 = relu(Vb @ Wh1 + bh1)   (N x 256)
    gemm_f32<<<dim3(rowTiles, 2), 256, 0, stream>>>(Vb, Wh1, bh1, nullptr, T1, N_NODES, 128, 256, 1);
    // t2 = T1 @ Wh2 + bh2 + Vb -> Kb (pre-BN2)
    gemm_f32<<<dim3(rowTiles, 1), 256, 0, stream>>>(T1, Wh2, bh2, Vb, Kb, N_NODES, 256, 128, 0);

    // BN2 -> out
    bn_stats<<<512, 256, 0, stream>>>(Kb, sums2);
    bn_finalize<<<1, 128, 0, stream>>>(sums2, mr2);
    bn_apply<<<2048, 256, 0, stream>>>(Kb, mr2, gamma, beta, out);
}

// Round 2
// 939.636 us; speedup vs baseline: 1.3625x; 1.3625x over previous
//
#include <hip/hip_runtime.h>
#include <hip/hip_bf16.h>
#include <math.h>

#define N_NODES 50000
#define E_EDGES 800000
#define D_DIM   128
#define H_HEADS 8

typedef __attribute__((ext_vector_type(8))) short short8;
typedef __attribute__((ext_vector_type(4))) float f32x4;
typedef unsigned int   uint_t;
typedef unsigned short ushort_t;

static __device__ __forceinline__ float4 ldg4(const float* p) {
    return *reinterpret_cast<const float4*>(p);
}
// f32 -> bf16 bits, round-to-nearest-even
static __device__ __forceinline__ ushort_t f2bf(float x) {
    union { float f; uint_t u; } v; v.f = x;
    uint_t r = v.u + 0x7fffu + ((v.u >> 16) & 1u);
    return (ushort_t)(r >> 16);
}
static __device__ __forceinline__ uint_t pk(float lo, float hi) {
    return (uint_t)f2bf(lo) | ((uint_t)f2bf(hi) << 16);
}

// ---------------- CSR build ----------------
__global__ void hist_kernel(const int* __restrict__ dst, int* __restrict__ hist) {
    int i = blockIdx.x * blockDim.x + threadIdx.x;
    if (i < E_EDGES) atomicAdd(&hist[dst[i]], 1);
}

__global__ __launch_bounds__(1024) void scan_kernel(const int* __restrict__ cnt,
                                                    int* __restrict__ start,
                                                    int* __restrict__ cursor) {
    __shared__ int sh[1024];
    const int t = threadIdx.x;
    const int CPT = (N_NODES + 1023) / 1024;
    int lo = t * CPT;
    int hi = lo + CPT; if (hi > N_NODES) hi = N_NODES; if (lo > N_NODES) lo = N_NODES;
    int s = 0;
    for (int i = lo; i < hi; i++) s += cnt[i];
    sh[t] = s;
    __syncthreads();
    for (int off = 1; off < 1024; off <<= 1) {
        int v = (t >= off) ? sh[t - off] : 0;
        __syncthreads();
        sh[t] += v;
        __syncthreads();
    }
    int run = sh[t] - s;
    for (int i = lo; i < hi; i++) {
        start[i]  = run;
        cursor[i] = run;
        run += cnt[i];
    }
    if (t == 1023) start[N_NODES] = sh[1023];
}

__global__ void scatter_kernel(const int* __restrict__ dst, int* __restrict__ cursor,
                               int* __restrict__ eids) {
    int i = blockIdx.x * blockDim.x + threadIdx.x;
    if (i < E_EDGES) {
        int p = atomicAdd(&cursor[dst[i]], 1);
        eids[p] = i;
    }
}

// ---------------- weight prep: bf16, transposed [col][k], XOR-swizzled, 16KB tiles ----------------
// tile layout: 128 cols x 64 k, byte = (col*128 + kl*2) ^ ((col&7)<<4)
// tiles: [0,6): Wq,Wk,Wv (2 each)  [6,8): We  [8,10): Wsdp  [10,14): Wh1 (cb-major)  [14,18): Wh2
__global__ __launch_bounds__(256) void prep_weights(const float* __restrict__ Wq,
                                                    const float* __restrict__ Wk,
                                                    const float* __restrict__ Wv,
                                                    const float* __restrict__ We,
                                                    const float* __restrict__ Wsdp,
                                                    const float* __restrict__ Wh1,
                                                    const float* __restrict__ Wh2,
                                                    ushort_t* __restrict__ prep) {
    const int b = blockIdx.x;
    const float* W; int ld, cb, kc;
    if (b < 6)       { W = (b < 2 ? Wq : (b < 4 ? Wk : Wv)); ld = 128; cb = 0; kc = b & 1; }
    else if (b < 8)  { W = We;   ld = 128; cb = 0;            kc = b - 6; }
    else if (b < 10) { W = Wsdp; ld = 128; cb = 0;            kc = b - 8; }
    else if (b < 14) { W = Wh1;  ld = 256; cb = (b - 10) >> 1; kc = (b - 10) & 1; }
    else             { W = Wh2;  ld = 128; cb = 0;            kc = b - 14; }
    char* tile = (char*)(prep + (size_t)b * 8192);
    for (int i = threadIdx.x; i < 8192; i += 256) {
        int col = i >> 6, kl = i & 63;
        int k = kc * 64 + kl;
        float v = W[(size_t)k * ld + cb * 128 + col];
        int byte = (col * 128 + kl * 2) ^ ((col & 7) << 4);
        *(ushort_t*)(tile + byte) = f2bf(v);
    }
}

// ---------------- bf16 MFMA GEMM: C = A[MxK] @ W[Kx128cols-per-cb] (+bias, relu, resid) ----------------
// 256 threads = 4 waves (2x2), tile 128x128, K chunks of 64.
__global__ __launch_bounds__(256) void gemm_bf16(const float* __restrict__ A,
                                                 int M, int K,
                                                 const ushort_t* __restrict__ Bt, int nkc,
                                                 const float* __restrict__ bias,
                                                 const float* __restrict__ resid,
                                                 float* __restrict__ C, int ldc,
                                                 size_t cbStride, int doRelu) {
    __shared__ __align__(16) unsigned char As[16384];   // [128 rows][64 k] bf16 swizzled
    __shared__ __align__(16) unsigned char Bs[16384];   // [128 cols][64 k] bf16 swizzled
    const int tid  = threadIdx.x;
    const int lane = tid & 63;
    const int wid  = tid >> 6;
    const int wr   = wid >> 1;       // 0..1  rows wr*64
    const int wc   = wid & 1;        // 0..1  cols wc*64
    const int cb   = blockIdx.y;
    const int row0 = blockIdx.x * 128;

    f32x4 acc[4][4];
#pragma unroll
    for (int i = 0; i < 4; i++)
#pragma unroll
        for (int j = 0; j < 4; j++) acc[i][j] = (f32x4){0.f, 0.f, 0.f, 0.f};

    for (int kc = 0; kc < nkc; kc++) {
        __syncthreads();
        {   // stage A chunk: 128 rows x 64 k, f32 -> bf16
            int row = tid >> 1;
            int kl0 = (tid & 1) * 32;
            int gr  = row0 + row;
            float4 v4[8];
            if (gr < M) {
                const float* ap = &A[(size_t)gr * K + kc * 64 + kl0];
#pragma unroll
                for (int j = 0; j < 8; j++) v4[j] = ldg4(ap + 4 * j);
            } else {
#pragma unroll
                for (int j = 0; j < 8; j++) v4[j] = make_float4(0.f, 0.f, 0.f, 0.f);
            }
            int s = (row & 7) << 4;
#pragma unroll
            for (int j = 0; j < 4; j++) {
                uint4 w;
                w.x = pk(v4[2 * j].x, v4[2 * j].y);
                w.y = pk(v4[2 * j].z, v4[2 * j].w);
                w.z = pk(v4[2 * j + 1].x, v4[2 * j + 1].y);
                w.w = pk(v4[2 * j + 1].z, v4[2 * j + 1].w);
                int byte = (row * 128 + (kl0 + 8 * j) * 2) ^ s;
                *(uint4*)(As + byte) = w;
            }
        }
        {   // stage B chunk: linear 16KB copy of prepped tile
            const uint4* gB = (const uint4*)(Bt + (size_t)(cb * nkc + kc) * 8192);
#pragma unroll
            for (int j = 0; j < 4; j++) {
                int idx = j * 256 + tid;
                ((uint4*)Bs)[idx] = gB[idx];
            }
        }
        __syncthreads();
#pragma unroll
        for (int k0 = 0; k0 < 64; k0 += 32) {
            short8 a[4], b[4];
#pragma unroll
            for (int mi = 0; mi < 4; mi++) {
                int row = wr * 64 + mi * 16 + (lane & 15);
                int byte = (row * 128 + k0 * 2 + (lane >> 4) * 16) ^ ((row & 7) << 4);
                a[mi] = *(const short8*)(As + byte);
            }
#pragma unroll
            for (int ni = 0; ni < 4; ni++) {
                int col = wc * 64 + ni * 16 + (lane & 15);
                int byte = (col * 128 + k0 * 2 + (lane >> 4) * 16) ^ ((col & 7) << 4);
                b[ni] = *(const short8*)(Bs + byte);
            }
#pragma unroll
            for (int mi = 0; mi < 4; mi++)
#pragma unroll
                for (int ni = 0; ni < 4; ni++)
                    acc[mi][ni] = __builtin_amdgcn_mfma_f32_16x16x32_bf16(a[mi], b[ni], acc[mi][ni], 0, 0, 0);
        }
    }
    // epilogue
#pragma unroll
    for (int mi = 0; mi < 4; mi++) {
#pragma unroll
        for (int r = 0; r < 4; r++) {
            int row = row0 + wr * 64 + mi * 16 + ((lane >> 4) << 2) + r;
            if (row < M) {
#pragma unroll
                for (int ni = 0; ni < 4; ni++) {
                    int col = wc * 64 + ni * 16 + (lane & 15);
                    float v = acc[mi][ni][r];
                    if (bias) v += bias[cb * 128 + col];
                    if (doRelu) v = fmaxf(v, 0.f);
                    if (resid) v += resid[(size_t)row * ldc + col];
                    C[cb * cbStride + (size_t)row * ldc + col] = v;
                }
            }
        }
    }
}

// ---------------- fused edge kernel: EF = e@We via MFMA, dot with k[src]*q[dst], exp ----------------
// 512 threads = 8 waves; 64 edges/block. Also writes the f32 e pass-through copy.
__global__ __launch_bounds__(512) void edge_mfma(const float* __restrict__ e,
                                                 const int* __restrict__ src,
                                                 const int* __restrict__ dst,
                                                 const float* __restrict__ Qm,
                                                 const float* __restrict__ Km,
                                                 const ushort_t* __restrict__ WeT,
                                                 float* __restrict__ S,
                                                 float* __restrict__ out_e) {
    __shared__ __align__(16) unsigned char Asm[16384];  // 2 chunks x [64 rows][64 k] bf16 swizzled
    __shared__ __align__(16) unsigned char Bsm[32768];  // 2 chunks x [128 cols][64 k] bf16 swizzled
    const int tid  = threadIdx.x;
    const int lane = tid & 63;
    const int wid  = tid >> 6;
    const int wr   = wid >> 2;       // 0..1 : rows wr*32
    const int wc   = wid & 3;        // 0..3 : cols wc*32 (heads 2wc, 2wc+1)
    const int e0   = blockIdx.x * 64;

    {   // stage e tile (f32 -> bf16 LDS) + f32 pass-through copy
        int row = tid >> 3;
        int c0  = (tid & 7) * 16;
        const float* ep = &e[(size_t)(e0 + row) * 128 + c0];
        float*       op = &out_e[(size_t)(e0 + row) * 128 + c0];
        float4 v4[4];
#pragma unroll
        for (int j = 0; j < 4; j++) v4[j] = ldg4(ep + 4 * j);
#pragma unroll
        for (int j = 0; j < 4; j++) *(float4*)(op + 4 * j) = v4[j];
        int chunk = c0 >> 6;
        int klb   = (c0 & 63) * 2;
        int s     = (row & 7) << 4;
        uint4 w0, w1;
        w0.x = pk(v4[0].x, v4[0].y); w0.y = pk(v4[0].z, v4[0].w);
        w0.z = pk(v4[1].x, v4[1].y); w0.w = pk(v4[1].z, v4[1].w);
        w1.x = pk(v4[2].x, v4[2].y); w1.y = pk(v4[2].z, v4[2].w);
        w1.z = pk(v4[3].x, v4[3].y); w1.w = pk(v4[3].z, v4[3].w);
        *(uint4*)(Asm + chunk * 8192 + ((row * 128 + klb) ^ s))      = w0;
        *(uint4*)(Asm + chunk * 8192 + ((row * 128 + klb + 16) ^ s)) = w1;
    }
    {   // stage WeT (already bf16+swizzled): linear 32KB copy
        const uint4* gB = (const uint4*)WeT;
#pragma unroll
        for (int j = 0; j < 4; j++) {
            int idx = j * 512 + tid;
            ((uint4*)Bsm)[idx] = gB[idx];
        }
    }
    __syncthreads();

    f32x4 acc[2][2];
#pragma unroll
    for (int i = 0; i < 2; i++)
#pragma unroll
        for (int j = 0; j < 2; j++) acc[i][j] = (f32x4){0.f, 0.f, 0.f, 0.f};

#pragma unroll
    for (int k0 = 0; k0 < 128; k0 += 32) {
        int chunk = k0 >> 6;
        int klb   = (k0 & 63) * 2;
        short8 a[2], b[2];
#pragma unroll
        for (int mi = 0; mi < 2; mi++) {
            int row = wr * 32 + mi * 16 + (lane & 15);
            int byte = chunk * 8192 + ((row * 128 + klb + (lane >> 4) * 16) ^ ((row & 7) << 4));
            a[mi] = *(const short8*)(Asm + byte);
        }
#pragma unroll
        for (int ni = 0; ni < 2; ni++) {
            int col = wc * 32 + ni * 16 + (lane & 15);
            int byte = chunk * 16384 + ((col * 128 + klb + (lane >> 4) * 16) ^ ((col & 7) << 4));
            b[ni] = *(const short8*)(Bsm + byte);
        }
#pragma unroll
        for (int mi = 0; mi < 2; mi++)
#pragma unroll
            for (int ni = 0; ni < 2; ni++)
                acc[mi][ni] = __builtin_amdgcn_mfma_f32_16x16x32_bf16(a[mi], b[ni], acc[mi][ni], 0, 0, 0);
    }

    // epilogue: score[e,h] = 0.25 * sum_d EF[e, h*16+d] * K[src][..] * Q[dst][..]
#pragma unroll
    for (int mi = 0; mi < 2; mi++) {
        int rows[4], sidx[4], didx[4];
#pragma unroll
        for (int r = 0; r < 4; r++) {
            rows[r] = e0 + wr * 32 + mi * 16 + ((lane >> 4) << 2) + r;
            sidx[r] = src[rows[r]];
            didx[r] = dst[rows[r]];
        }
#pragma unroll
        for (int ni = 0; ni < 2; ni++) {
            int head = wc * 2 + ni;
            int col  = head * 16 + (lane & 15);
            float pv[4];
#pragma unroll
            for (int r = 0; r < 4; r++) {
                float kv = Km[(size_t)sidx[r] * 128 + col];
                float qv = Qm[(size_t)didx[r] * 128 + col];
                pv[r] = acc[mi][ni][r] * kv * qv;
            }
#pragma unroll
            for (int off = 1; off < 16; off <<= 1)
#pragma unroll
                for (int r = 0; r < 4; r++) pv[r] += __shfl_xor(pv[r], off, 64);
            if ((lane & 15) == 0) {
#pragma unroll
                for (int r = 0; r < 4; r++) {
                    float v = 0.25f * pv[r];
                    v = fminf(fmaxf(v, -5.f), 5.f);
                    S[(size_t)head * E_EDGES + rows[r]] = __expf(v);
                }
            }
        }
    }
}

// ---------------- aggregation: per-dst-node sum over CSR edges ----------------
__global__ __launch_bounds__(128) void agg_kernel(const float* __restrict__ V,
                                                  const float* __restrict__ S,
                                                  const int* __restrict__ start,
                                                  const int* __restrict__ eids,
                                                  const int* __restrict__ src,
                                                  float* __restrict__ HA) {
    const int n = blockIdx.x;
    const int t = threadIdx.x;
    const int h = t >> 4;
    const int s0 = start[n];
    const int s1 = start[n + 1];
    float acc = 0.f, z = 0.f;
    for (int i = s0; i < s1; i++) {
        int eid = eids[i];
        float sv = S[(size_t)h * E_EDGES + eid];
        float vv = V[(size_t)src[eid] * 128 + t];
        acc = fmaf(sv, vv, acc);
        z += sv;
    }
    HA[(size_t)n * 128 + t] = acc / (z + 1e-6f);
}

// ---------------- batch norm ----------------
__global__ __launch_bounds__(256) void bn_stats(const float* __restrict__ X,
                                                float* __restrict__ sums) {
    __shared__ float s1[256], s2[256];
    const int tid = threadIdx.x;
    float a1 = 0.f, a2 = 0.f;
    const size_t total = (size_t)N_NODES * 128;
    for (size_t i = (size_t)blockIdx.x * 256 + tid; i < total; i += (size_t)gridDim.x * 256) {
        float v = X[i];
        a1 += v;
        a2 += v * v;
    }
    s1[tid] = a1; s2[tid] = a2;
    __syncthreads();
    if (tid < 128) {
        a1 = s1[tid] + s1[tid + 128];
        a2 = s2[tid] + s2[tid + 128];
        atomicAdd(&sums[tid], a1);
        atomicAdd(&sums[128 + tid], a2);
    }
}

__global__ void bn_finalize(const float* __restrict__ sums, float* __restrict__ mu_rstd) {
    int c = threadIdx.x;
    float mu  = sums[c] * (1.f / (float)N_NODES);
    float var = sums[128 + c] * (1.f / (float)N_NODES) - mu * mu;
    mu_rstd[c]       = mu;
    mu_rstd[128 + c] = rsqrtf(var + 1e-5f);
}

__global__ __launch_bounds__(256) void bn_apply(const float* __restrict__ X,
                                                const float* __restrict__ mu_rstd,
                                                const float* __restrict__ gamma,
                                                const float* __restrict__ beta,
                                                float* __restrict__ Y) {
    const size_t total = (size_t)N_NODES * 128;
    const size_t step = (size_t)gridDim.x * blockDim.x * 4;
    for (size_t i = ((size_t)blockIdx.x * blockDim.x + threadIdx.x) * 4; i < total; i += step) {
        float4 x = ldg4(&X[i]);
        int c = (int)(i & 127);
        float4 y;
        y.x = (x.x - mu_rstd[c + 0]) * mu_rstd[128 + c + 0] * gamma[c + 0] + beta[c + 0];
        y.y = (x.y - mu_rstd[c + 1]) * mu_rstd[128 + c + 1] * gamma[c + 1] + beta[c + 1];
        y.z = (x.z - mu_rstd[c + 2]) * mu_rstd[128 + c + 2] * gamma[c + 2] + beta[c + 2];
        y.w = (x.w - mu_rstd[c + 3]) * mu_rstd[128 + c + 3] * gamma[c + 3] + beta[c + 3];
        *reinterpret_cast<float4*>(&Y[i]) = y;
    }
}

extern "C" void kernel_launch(void* const* d_in, const int* in_sizes, int n_in,
                              void* d_out, int out_size, void* d_ws, size_t ws_size,
                              hipStream_t stream) {
    (void)in_sizes; (void)n_in; (void)out_size; (void)ws_size;
    const int*   src   = (const int*)d_in[0];
    const int*   dst   = (const int*)d_in[1];
    const float* h     = (const float*)d_in[2];
    const float* e     = (const float*)d_in[3];
    const float* Wq    = (const float*)d_in[5];
    const float* Wk    = (const float*)d_in[6];
    const float* Wv    = (const float*)d_in[7];
    const float* We    = (const float*)d_in[8];
    const float* Wsdp  = (const float*)d_in[9];
    const float* bsdp  = (const float*)d_in[10];
    const float* Wh1   = (const float*)d_in[11];
    const float* bh1   = (const float*)d_in[12];
    const float* Wh2   = (const float*)d_in[13];
    const float* bh2   = (const float*)d_in[14];
    const float* gamma = (const float*)d_in[15];
    const float* beta  = (const float*)d_in[16];
    float* out = (float*)d_out;

    float* ws = (float*)d_ws;
    const size_t NM = (size_t)N_NODES * 128;   // 6.4M floats
    float* Qb    = ws;               // q; later h_attn
    float* Kb    = ws + NM;          // k; later pre-BN1, later pre-BN2
    float* Vb    = ws + 2 * NM;      // v; later bn1 output
    float* Sb    = ws + 3 * NM;      // edge scores [H][E] (8*800000 = 6.4M)
    float* T1    = ws + 4 * NM;      // FFN hidden N x 256
    float* STATS = ws + 6 * NM;
    int* hist   = (int*)(STATS + 1024);
    int* startp = hist + N_NODES;
    int* cursor = startp + N_NODES + 1;
    int* eids   = cursor + N_NODES;
    ushort_t* prep = (ushort_t*)(eids + E_EDGES);   // 18 tiles x 8192 ushorts

    float* sums1 = STATS;
    float* mr1   = STATS + 256;
    float* sums2 = STATS + 512;
    float* mr2   = STATS + 768;

    // weight prep (bf16, transposed, swizzled)
    prep_weights<<<18, 256, 0, stream>>>(Wq, Wk, Wv, We, Wsdp, Wh1, Wh2, prep);

    // zero stats + histogram
    hipMemsetAsync(STATS, 0, (1024 + N_NODES) * sizeof(float), stream);

    // CSR build
    hist_kernel<<<(E_EDGES + 255) / 256, 256, 0, stream>>>(dst, hist);
    scan_kernel<<<1, 1024, 0, stream>>>(hist, startp, cursor);
    scatter_kernel<<<(E_EDGES + 255) / 256, 256, 0, stream>>>(dst, cursor, eids);

    const int rowTiles = (N_NODES + 127) / 128;   // 391

    // q,k,v in one launch: cb = matrix, outputs contiguous (Qb,Kb,Vb)
    gemm_bf16<<<dim3(rowTiles, 3), 256, 0, stream>>>(h, N_NODES, 128, prep, 2,
                                                     nullptr, nullptr, Qb, 128, NM, 0);

    // fused edge scores + e pass-through copy
    edge_mfma<<<E_EDGES / 64, 512, 0, stream>>>(e, src, dst, Qb, Kb, prep + (size_t)6 * 8192,
                                                Sb, out + NM);

    // aggregation -> h_attn (into Qb)
    agg_kernel<<<N_NODES, 128, 0, stream>>>(Vb, Sb, startp, eids, src, Qb);

    // sdp projection + residual h -> Kb (pre-BN1)
    gemm_bf16<<<dim3(rowTiles, 1), 256, 0, stream>>>(Qb, N_NODES, 128, prep + (size_t)8 * 8192, 2,
                                                     bsdp, h, Kb, 128, 0, 0);

    // BN1 -> Vb
    bn_stats<<<512, 256, 0, stream>>>(Kb, sums1);
    bn_finalize<<<1, 128, 0, stream>>>(sums1, mr1);
    bn_apply<<<2048, 256, 0, stream>>>(Kb, mr1, gamma, beta, Vb);

    // FFN1: T1 = relu(Vb @ Wh1 + bh1)  (N x 256)
    gemm_bf16<<<dim3(rowTiles, 2), 256, 0, stream>>>(Vb, N_NODES, 128, prep + (size_t)10 * 8192, 2,
                                                     bh1, nullptr, T1, 256, 128, 1);
    // FFN2: Kb = T1 @ Wh2 + bh2 + Vb (pre-BN2)
    gemm_bf16<<<dim3(rowTiles, 1), 256, 0, stream>>>(T1, N_NODES, 256, prep + (size_t)14 * 8192, 4,
                                                     bh2, Vb, Kb, 128, 0, 0);

    // BN2 -> out
    bn_stats<<<512, 256, 0, stream>>>(Kb, sums2);
    bn_finalize<<<1, 128, 0, stream>>>(sums2, mr2);
    bn_apply<<<2048, 256, 0, stream>>>(Kb, mr2, gamma, beta, out);
}